// Round 1
// baseline (9343.468 us; speedup 1.0000x reference)
//
#include <hip/hip_runtime.h>
#include <cstdint>
#include <cstddef>

// ---------------------------------------------------------------------------
// Submanifold sparse conv net (7 levels x 2 SubMConv3d + SparseMaxPool3d).
// All structure building happens on-GPU (graph-capture safe, fixed dims,
// device-side counts guard every kernel).
// ---------------------------------------------------------------------------

static inline int cdiv_h(int a, int b) { return (a + b - 1) / b; }

__global__ void set_count_k(int* counts, int n) { counts[0] = n; }

// grid[lin(z,y,x)] = row index
__global__ void scatter_grid_k(const int* __restrict__ coords, const int* __restrict__ cnt,
                               int* __restrict__ grid, int S)
{
    int i = blockIdx.x * blockDim.x + threadIdx.x;
    if (i >= cnt[0]) return;
    int z = coords[i * 4 + 1], y = coords[i * 4 + 2], x = coords[i * 4 + 3];
    grid[(z * S + y) * S + x] = i;
}

// pairs[k][i] = row of neighbor at offset k, or -1
__global__ void build_pairs_k(const int* __restrict__ coords, const int* __restrict__ cnt,
                              const int* __restrict__ grid, int* __restrict__ pairs,
                              int pstride, int S)
{
    int i = blockIdx.x * blockDim.x + threadIdx.x;
    if (i >= cnt[0]) return;
    int z = coords[i * 4 + 1], y = coords[i * 4 + 2], x = coords[i * 4 + 3];
#pragma unroll
    for (int k = 0; k < 27; ++k) {
        int nz = z + k / 9 - 1;
        int ny = y + (k / 3) % 3 - 1;
        int nx = x + k % 3 - 1;
        int v = -1;
        if (nz >= 0 && nz < S && ny >= 0 && ny < S && nx >= 0 && nx < S)
            v = grid[(nz * S + ny) * S + nx];
        pairs[(size_t)k * pstride + i] = v;
    }
}

// out[i, cg:cg+4] = sum_k feats[pairs[k][i]] @ W[k][:, cg:cg+4]
template <int CIN, int COUT>
__global__ __launch_bounds__(256) void subm_conv_k(
    const float* __restrict__ fin, const float* __restrict__ W,
    const int* __restrict__ pairs, const int* __restrict__ cnt,
    float* __restrict__ fout, int pstride)
{
    constexpr int G   = COUT / 4;   // cout-groups per row
    constexpr int RPB = 256 / G;    // rows per block (floor)
    const int lr = (int)threadIdx.x / G;
    const int cg = ((int)threadIdx.x % G) * 4;
    if (256 % G != 0 && lr >= RPB) return;
    const int row = blockIdx.x * RPB + lr;
    if (row >= cnt[0]) return;

    float a0 = 0.f, a1 = 0.f, a2 = 0.f, a3 = 0.f;
    for (int k = 0; k < 27; ++k) {
        const int nb = pairs[(size_t)k * pstride + row];
        if (nb < 0) continue;
        const float* __restrict__ frow = fin + (size_t)nb * CIN;
        const float* __restrict__ wk   = W + (size_t)k * CIN * COUT + cg;
        if constexpr (CIN % 4 == 0) {
#pragma unroll 2
            for (int ci = 0; ci < CIN; ci += 4) {
                const float4 f  = *reinterpret_cast<const float4*>(frow + ci);
                const float* wp = wk + (size_t)ci * COUT;
                const float4 w0 = *reinterpret_cast<const float4*>(wp);
                const float4 w1 = *reinterpret_cast<const float4*>(wp + COUT);
                const float4 w2 = *reinterpret_cast<const float4*>(wp + 2 * COUT);
                const float4 w3 = *reinterpret_cast<const float4*>(wp + 3 * COUT);
                a0 += f.x * w0.x + f.y * w1.x + f.z * w2.x + f.w * w3.x;
                a1 += f.x * w0.y + f.y * w1.y + f.z * w2.y + f.w * w3.y;
                a2 += f.x * w0.z + f.y * w1.z + f.z * w2.z + f.w * w3.z;
                a3 += f.x * w0.w + f.y * w1.w + f.z * w2.w + f.w * w3.w;
            }
        } else {
#pragma unroll
            for (int ci = 0; ci < CIN; ++ci) {
                const float  f = frow[ci];
                const float4 w = *reinterpret_cast<const float4*>(wk + (size_t)ci * COUT);
                a0 += f * w.x; a1 += f * w.y; a2 += f * w.z; a3 += f * w.w;
            }
        }
    }
    float4 r; r.x = a0; r.y = a1; r.z = a2; r.w = a3;
    *reinterpret_cast<float4*>(fout + (size_t)row * COUT + cg) = r;
}

// mark pooled-cell occupancy
__global__ void mark_occ_k(const int* __restrict__ coords, const int* __restrict__ cnt,
                           int* __restrict__ occ, int Sh)
{
    int i = blockIdx.x * blockDim.x + threadIdx.x;
    if (i >= cnt[0]) return;
    int z = coords[i * 4 + 1] >> 1, y = coords[i * 4 + 2] >> 1, x = coords[i * 4 + 3] >> 1;
    occ[(z * Sh + y) * Sh + x] = 1;
}

// single-block sequential-chunk exclusive scan over occupancy grid ->
// ranks in ascending linear-cell order (== np.unique sorted order).
// Writes newcoords[rank] = (0,z,y,x) and *cntOut = M.
__global__ __launch_bounds__(1024) void scan_occ_k(
    const int* __restrict__ occ, int P,
    int* __restrict__ newcoords, int* __restrict__ cntOut, int Sh)
{
    __shared__ int lds[1024];
    __shared__ int running;
    if (threadIdx.x == 0) running = 0;
    __syncthreads();
    const int SS = Sh * Sh;
    for (int base = 0; base < P; base += 8192) {
        int i0 = base + (int)threadIdx.x * 8;
        int v[8];
        int s = 0;
#pragma unroll
        for (int j = 0; j < 8; ++j) {
            v[j] = (i0 + j < P) ? occ[i0 + j] : 0;
            s += v[j];
        }
        lds[threadIdx.x] = s;
        __syncthreads();
        for (int off = 1; off < 1024; off <<= 1) {
            int t = (threadIdx.x >= (unsigned)off) ? lds[threadIdx.x - off] : 0;
            __syncthreads();
            lds[threadIdx.x] += t;
            __syncthreads();
        }
        int incl = lds[threadIdx.x];
        int r = running + incl - s;  // exclusive prefix
#pragma unroll
        for (int j = 0; j < 8; ++j) {
            if (v[j]) {
                int c = i0 + j;
                newcoords[r * 4 + 0] = 0;
                newcoords[r * 4 + 1] = c / SS;
                newcoords[r * 4 + 2] = (c % SS) / Sh;
                newcoords[r * 4 + 3] = c % Sh;
                ++r;
            }
        }
        __syncthreads();
        if (threadIdx.x == 1023) running += incl;
        __syncthreads();
    }
    if (threadIdx.x == 0) *cntOut = running;
}

// max over the (up to) 8 children of each pooled site, via prev-level grid
__global__ void pool_max_k(const float* __restrict__ fin, const int* __restrict__ gridPrev,
                           const int* __restrict__ newcoords, const int* __restrict__ cnt,
                           float* __restrict__ fout, int C, int Sprev)
{
    int idx = blockIdx.x * blockDim.x + threadIdx.x;
    int r = idx / C, c = idx % C;
    if (r >= cnt[0]) return;
    int z2 = newcoords[r * 4 + 1] * 2;
    int y2 = newcoords[r * 4 + 2] * 2;
    int x2 = newcoords[r * 4 + 3] * 2;
    float v = -3.4e38f;
#pragma unroll
    for (int d = 0; d < 8; ++d) {
        int z = z2 + (d >> 2), y = y2 + ((d >> 1) & 1), x = x2 + (d & 1);
        int j = gridPrev[(z * Sprev + y) * Sprev + x];
        if (j >= 0) v = fmaxf(v, fin[(size_t)j * C + c]);
    }
    fout[(size_t)r * C + c] = v;
}

// ---------------------------------------------------------------------------

template <int CIN, int COUT>
static void launch_conv(const float* fin, const float* W, const int* pairs,
                        const int* cnt, float* fout, int bound, int pstride,
                        hipStream_t stream)
{
    constexpr int G   = COUT / 4;
    constexpr int RPB = 256 / G;
    int blocks = cdiv_h(bound, RPB);
    subm_conv_k<CIN, COUT><<<blocks, 256, 0, stream>>>(fin, W, pairs, cnt, fout, pstride);
}

extern "C" void kernel_launch(void* const* d_in, const int* in_sizes, int n_in,
                              void* d_out, int out_size, void* d_ws, size_t ws_size,
                              hipStream_t stream)
{
    const float* feats0 = (const float*)d_in[0];
    const int*   coors  = (const int*)d_in[1];
    const float* w[14];
    for (int i = 0; i < 14; ++i) w[i] = (const float*)d_in[3 + i];
    float* out = (float*)d_out;

    const int N = in_sizes[0] / 3;

    // ---- workspace carve-up (all 16B-aligned) ----
    char* p = (char*)d_ws;
    int* grid    = (int*)p;  p += (size_t)128 * 128 * 128 * 4;  // 8 MB
    int* occ     = (int*)p;  p += (size_t)64 * 64 * 64 * 4;     // 1 MB
    int* counts  = (int*)p;  p += 256;
    int* pairs   = (int*)p;  p += (size_t)27 * N * 4;
    int* coordsA = (int*)p;  p += (size_t)N * 16;
    int* coordsB = (int*)p;  p += (size_t)N * 16;
    size_t bufElems = (size_t)N * 96;
    if (bufElems < (size_t)32768 * 128) bufElems = (size_t)32768 * 128;
    float* bufA = (float*)p; p += bufElems * 4;
    float* bufB = (float*)p;

    int bounds[7];
    for (int l = 0; l < 7; ++l) {
        int S = 128 >> l;
        int c = S * S * S;
        bounds[l] = N < c ? N : c;
    }

    set_count_k<<<1, 1, 0, stream>>>(counts, N);
    hipMemsetAsync(d_out, 0, (size_t)out_size * 4, stream);

    auto build_level = [&](const int* coordsL, int lvl) {
        int S = 128 >> lvl;
        hipMemsetAsync(grid, 0xFF, (size_t)S * S * S * 4, stream);
        int blocks = cdiv_h(bounds[lvl], 256);
        scatter_grid_k<<<blocks, 256, 0, stream>>>(coordsL, counts + lvl, grid, S);
        build_pairs_k<<<blocks, 256, 0, stream>>>(coordsL, counts + lvl, grid, pairs, N, S);
    };

    auto do_pool = [&](const int* coordsL, int lvl, const float* fin, float* fout,
                       int C, int* coordsOut) {
        int S = 128 >> lvl, Sh = S / 2, P = Sh * Sh * Sh;
        hipMemsetAsync(occ, 0, (size_t)P * 4, stream);
        mark_occ_k<<<cdiv_h(bounds[lvl], 256), 256, 0, stream>>>(coordsL, counts + lvl, occ, Sh);
        scan_occ_k<<<1, 1024, 0, stream>>>(occ, P, coordsOut, counts + lvl + 1, Sh);
        int total = bounds[lvl + 1] * C;
        pool_max_k<<<cdiv_h(total, 256), 256, 0, stream>>>(fin, grid, coordsOut,
                                                           counts + lvl + 1, fout, C, S);
    };

    // ---- level 0 ----
    build_level(coors, 0);
    launch_conv<3, 64>(feats0, w[0], pairs, counts + 0, bufA, bounds[0], N, stream);
    launch_conv<64, 64>(bufA, w[1], pairs, counts + 0, bufB, bounds[0], N, stream);
    do_pool(coors, 0, bufB, bufA, 64, coordsA);
    // ---- level 1 ----
    build_level(coordsA, 1);
    launch_conv<64, 96>(bufA, w[2], pairs, counts + 1, bufB, bounds[1], N, stream);
    launch_conv<96, 96>(bufB, w[3], pairs, counts + 1, bufA, bounds[1], N, stream);
    do_pool(coordsA, 1, bufA, bufB, 96, coordsB);
    // ---- level 2 ----
    build_level(coordsB, 2);
    launch_conv<96, 128>(bufB, w[4], pairs, counts + 2, bufA, bounds[2], N, stream);
    launch_conv<128, 128>(bufA, w[5], pairs, counts + 2, bufB, bounds[2], N, stream);
    do_pool(coordsB, 2, bufB, bufA, 128, coordsA);
    // ---- level 3 ----
    build_level(coordsA, 3);
    launch_conv<128, 160>(bufA, w[6], pairs, counts + 3, bufB, bounds[3], N, stream);
    launch_conv<160, 160>(bufB, w[7], pairs, counts + 3, bufA, bounds[3], N, stream);
    do_pool(coordsA, 3, bufA, bufB, 160, coordsB);
    // ---- level 4 ----
    build_level(coordsB, 4);
    launch_conv<160, 192>(bufB, w[8], pairs, counts + 4, bufA, bounds[4], N, stream);
    launch_conv<192, 192>(bufA, w[9], pairs, counts + 4, bufB, bounds[4], N, stream);
    do_pool(coordsB, 4, bufB, bufA, 192, coordsA);
    // ---- level 5 ----
    build_level(coordsA, 5);
    launch_conv<192, 224>(bufA, w[10], pairs, counts + 5, bufB, bounds[5], N, stream);
    launch_conv<224, 224>(bufB, w[11], pairs, counts + 5, bufA, bounds[5], N, stream);
    do_pool(coordsA, 5, bufA, bufB, 224, coordsB);
    // ---- level 6 ----
    build_level(coordsB, 6);
    launch_conv<224, 256>(bufB, w[12], pairs, counts + 6, bufA, bounds[6], N, stream);
    launch_conv<256, 256>(bufA, w[13], pairs, counts + 6, out, bounds[6], N, stream);
}

// Round 2
// 1165.078 us; speedup vs baseline: 8.0196x; 8.0196x over previous
//
#include <hip/hip_runtime.h>
#include <cstdint>
#include <cstddef>

// ---------------------------------------------------------------------------
// Submanifold sparse conv net, MFMA bf16 implicit-GEMM version.
// Structure (pairs, pooled coords) built on-GPU; all counts device-side.
// ---------------------------------------------------------------------------

typedef __attribute__((ext_vector_type(8))) short short8v;
typedef __attribute__((ext_vector_type(4))) float f32x4;

static inline int cdiv_h(int a, int b) { return (a + b - 1) / b; }

__device__ inline unsigned short f2bf(float f) {
    unsigned int u = __builtin_bit_cast(unsigned int, f);
    u += 0x7FFFu + ((u >> 16) & 1u);
    return (unsigned short)(u >> 16);
}
__device__ inline float bf2f(unsigned short h) {
    unsigned int u = ((unsigned int)h) << 16;
    return __builtin_bit_cast(float, u);
}

__global__ void set_count_k(int* counts, int n) { counts[0] = n; }

__global__ void scatter_grid_k(const int* __restrict__ coords, const int* __restrict__ cnt,
                               int* __restrict__ grid, int S)
{
    int i = blockIdx.x * blockDim.x + threadIdx.x;
    if (i >= cnt[0]) return;
    int z = coords[i * 4 + 1], y = coords[i * 4 + 2], x = coords[i * 4 + 3];
    grid[(z * S + y) * S + x] = i;
}

__global__ void build_pairs_k(const int* __restrict__ coords, const int* __restrict__ cnt,
                              const int* __restrict__ grid, int* __restrict__ pairs,
                              int pstride, int S)
{
    int i = blockIdx.x * blockDim.x + threadIdx.x;
    if (i >= cnt[0]) return;
    int z = coords[i * 4 + 1], y = coords[i * 4 + 2], x = coords[i * 4 + 3];
#pragma unroll
    for (int k = 0; k < 27; ++k) {
        int nz = z + k / 9 - 1;
        int ny = y + (k / 3) % 3 - 1;
        int nx = x + k % 3 - 1;
        int v = -1;
        if (nz >= 0 && nz < S && ny >= 0 && ny < S && nx >= 0 && nx < S)
            v = grid[(nz * S + ny) * S + nx];
        pairs[(size_t)k * pstride + i] = v;
    }
}

// ---- weight pre-pack: fp32 [27][CIN][COUT] -> bf16 fragment tiles -----------
// tile id = (k*NS + s)*NT + t ; within tile, lane l holds 8 contiguous bf16 =
// W[k][s*32 + (l>>4)*8 + j][t*16 + (l&15)], j=0..7.  (matches A's k mapping)
__global__ void pack_w_k(const float* __restrict__ W, unsigned short* __restrict__ Wp,
                         int CIN, int COUT)
{
    int NS = CIN >> 5, NT = COUT >> 4;
    int ntiles = 27 * NS * NT;
    int i = blockIdx.x * 256 + threadIdx.x;
    int tile = i >> 6, lane = i & 63;
    if (tile >= ntiles) return;
    int t = tile % NT;
    int s = (tile / NT) % NS;
    int k = tile / (NT * NS);
    int kabs = s * 32 + (lane >> 4) * 8;
    int c = t * 16 + (lane & 15);
    const float* src = W + ((size_t)(k * CIN + kabs)) * COUT + c;
    unsigned short* dst = Wp + (size_t)tile * 512 + lane * 8;
#pragma unroll
    for (int j = 0; j < 8; ++j) dst[j] = f2bf(src[(size_t)j * COUT]);
}

// ---- first layer (CIN=3) fp32 vector, writes bf16 ---------------------------
__global__ __launch_bounds__(256) void conv0_k(
    const float* __restrict__ fin, const float* __restrict__ W,
    const int* __restrict__ pairs, const int* __restrict__ cnt,
    unsigned short* __restrict__ fout, int pstride)
{
    const int row = blockIdx.x * 16 + ((int)threadIdx.x >> 4);
    const int cg = ((int)threadIdx.x & 15) * 4;
    if (row >= cnt[0]) return;
    float a0 = 0, a1 = 0, a2 = 0, a3 = 0;
    for (int k = 0; k < 27; ++k) {
        int nb = pairs[(size_t)k * pstride + row];
        if (nb < 0) continue;
        const float* fr = fin + (size_t)nb * 3;
        const float* wk = W + (size_t)k * 3 * 64 + cg;
#pragma unroll
        for (int ci = 0; ci < 3; ++ci) {
            float f = fr[ci];
            float4 w = *reinterpret_cast<const float4*>(wk + ci * 64);
            a0 += f * w.x; a1 += f * w.y; a2 += f * w.z; a3 += f * w.w;
        }
    }
    size_t o = (size_t)row * 64 + cg;
    fout[o] = f2bf(a0); fout[o + 1] = f2bf(a1);
    fout[o + 2] = f2bf(a2); fout[o + 3] = f2bf(a3);
}

// ---- MFMA conv: block = 4 waves, wave = RT row-tiles x CT cout-tiles --------
template <int CIN, int COUT, int RT, int CT, bool OUTF32>
__global__ __launch_bounds__(256) void conv_mfma_k(
    const unsigned short* __restrict__ fin, const unsigned short* __restrict__ Wp,
    const int* __restrict__ pairs, const int* __restrict__ cnt,
    void* __restrict__ fout, int pstride)
{
    constexpr int NS = CIN / 32, NT = COUT / 16;
    const int lane = (int)threadIdx.x & 63;
    const int wave = (int)threadIdx.x >> 6;
    const int l15 = lane & 15, lhi = lane >> 4;
    const int M = cnt[0];
    const int rowBase = (blockIdx.x * 4 + wave) * (RT * 16);
    if (rowBase >= M) return;
    const int ct0 = blockIdx.y * CT;

    f32x4 acc[RT][CT];
#pragma unroll
    for (int a = 0; a < RT; ++a)
#pragma unroll
        for (int b = 0; b < CT; ++b) acc[a][b] = (f32x4){0.f, 0.f, 0.f, 0.f};

    for (int k = 0; k < 27; ++k) {
        int nb[RT];
        int act[RT];
        bool anyAct = false;
#pragma unroll
        for (int rt = 0; rt < RT; ++rt) {
            int r = rowBase + rt * 16 + l15;
            nb[rt] = (r < M) ? pairs[(size_t)k * pstride + r] : -1;
        }
#pragma unroll
        for (int rt = 0; rt < RT; ++rt) {
            act[rt] = __any(nb[rt] >= 0);
            anyAct = anyAct || (act[rt] != 0);
        }
        if (!anyAct) continue;

        const unsigned short* wk = Wp + ((size_t)k * NS) * NT * 512;
#pragma unroll
        for (int s = 0; s < NS; ++s) {
            short8v bfrag[CT];
#pragma unroll
            for (int t = 0; t < CT; ++t)
                bfrag[t] = *reinterpret_cast<const short8v*>(
                    wk + ((size_t)s * NT + ct0 + t) * 512 + lane * 8);
#pragma unroll
            for (int rt = 0; rt < RT; ++rt) {
                if (!act[rt]) continue;
                short8v afrag = {};
                if (nb[rt] >= 0)
                    afrag = *reinterpret_cast<const short8v*>(
                        fin + (size_t)nb[rt] * CIN + s * 32 + lhi * 8);
#pragma unroll
                for (int t = 0; t < CT; ++t)
                    acc[rt][t] = __builtin_amdgcn_mfma_f32_16x16x32_bf16(
                        afrag, bfrag[t], acc[rt][t], 0, 0, 0);
            }
        }
    }

    // epilogue: C layout col = lane&15, row = (lane>>4)*4 + reg
#pragma unroll
    for (int rt = 0; rt < RT; ++rt) {
#pragma unroll
        for (int j = 0; j < 4; ++j) {
            int r = rowBase + rt * 16 + lhi * 4 + j;
            if (r >= M) continue;
#pragma unroll
            for (int t = 0; t < CT; ++t) {
                int c = (ct0 + t) * 16 + l15;
                if constexpr (OUTF32)
                    ((float*)fout)[(size_t)r * COUT + c] = acc[rt][t][j];
                else
                    ((unsigned short*)fout)[(size_t)r * COUT + c] = f2bf(acc[rt][t][j]);
            }
        }
    }
}

// ---- pooling structure: multi-block scan ------------------------------------
__global__ void mark_occ_k(const int* __restrict__ coords, const int* __restrict__ cnt,
                           int* __restrict__ occ, int Sh)
{
    int i = blockIdx.x * blockDim.x + threadIdx.x;
    if (i >= cnt[0]) return;
    int z = coords[i * 4 + 1] >> 1, y = coords[i * 4 + 2] >> 1, x = coords[i * 4 + 3] >> 1;
    occ[(z * Sh + y) * Sh + x] = 1;
}

__global__ __launch_bounds__(256) void scan_sum_k(const int* __restrict__ occ, int P,
                                                  int* __restrict__ bsum)
{
    int base = blockIdx.x * 4096 + (int)threadIdx.x * 16;
    int s = 0;
#pragma unroll
    for (int j = 0; j < 16; ++j) { int i = base + j; s += (i < P) ? occ[i] : 0; }
    for (int off = 1; off < 64; off <<= 1) s += __shfl_xor(s, off);
    __shared__ int ws[4];
    if ((threadIdx.x & 63) == 0) ws[threadIdx.x >> 6] = s;
    __syncthreads();
    if (threadIdx.x == 0) bsum[blockIdx.x] = ws[0] + ws[1] + ws[2] + ws[3];
}

__global__ void scan_offsets_k(const int* __restrict__ bsum, int nb,
                               int* __restrict__ boff, int* __restrict__ cntOut)
{
    int lane = threadIdx.x;  // 64 threads, nb <= 64
    int v = (lane < nb) ? bsum[lane] : 0;
    int incl = v;
    for (int off = 1; off < 64; off <<= 1) {
        int t = __shfl_up(incl, off);
        if (lane >= off) incl += t;
    }
    if (lane < nb) boff[lane] = incl - v;
    if (lane == 63) cntOut[0] = incl;
}

__global__ __launch_bounds__(256) void scan_emit_k(const int* __restrict__ occ, int P,
                                                   const int* __restrict__ boff,
                                                   int* __restrict__ newcoords, int Sh)
{
    __shared__ int ws[4];
    int tid = threadIdx.x;
    int base = blockIdx.x * 4096 + tid * 16;
    int v[16];
    int s = 0;
#pragma unroll
    for (int j = 0; j < 16; ++j) { int i = base + j; v[j] = (i < P) ? occ[i] : 0; s += v[j]; }
    int mysum = s;
    int incl = s;
    for (int off = 1; off < 64; off <<= 1) {
        int t = __shfl_up(incl, off);
        if ((tid & 63) >= off) incl += t;
    }
    if ((tid & 63) == 63) ws[tid >> 6] = incl;
    __syncthreads();
    int waveOff = 0;
    for (int w = 0; w < (tid >> 6); ++w) waveOff += ws[w];
    int r = boff[blockIdx.x] + waveOff + incl - mysum;
    const int SS = Sh * Sh;
#pragma unroll
    for (int j = 0; j < 16; ++j) {
        if (v[j]) {
            int c = base + j;
            newcoords[r * 4 + 0] = 0;
            newcoords[r * 4 + 1] = c / SS;
            newcoords[r * 4 + 2] = (c % SS) / Sh;
            newcoords[r * 4 + 3] = c % Sh;
            ++r;
        }
    }
}

__global__ void pool_max_k(const unsigned short* __restrict__ fin, const int* __restrict__ gridPrev,
                           const int* __restrict__ newcoords, const int* __restrict__ cnt,
                           unsigned short* __restrict__ fout, int C, int Sprev)
{
    int idx = blockIdx.x * blockDim.x + threadIdx.x;
    int r = idx / C, c = idx % C;
    if (r >= cnt[0]) return;
    int z2 = newcoords[r * 4 + 1] * 2;
    int y2 = newcoords[r * 4 + 2] * 2;
    int x2 = newcoords[r * 4 + 3] * 2;
    float best = -3.4e38f;
    unsigned short bb = 0;
#pragma unroll
    for (int d = 0; d < 8; ++d) {
        int z = z2 + (d >> 2), y = y2 + ((d >> 1) & 1), x = x2 + (d & 1);
        int j = gridPrev[(z * Sprev + y) * Sprev + x];
        if (j >= 0) {
            unsigned short u = fin[(size_t)j * C + c];
            float f = bf2f(u);
            if (f > best) { best = f; bb = u; }
        }
    }
    fout[(size_t)r * C + c] = bb;
}

// ---------------------------------------------------------------------------

template <int CIN, int COUT, int RT, int CT, bool OUTF32>
static void launch_cm(const unsigned short* fin, const unsigned short* Wp,
                      const int* pairs, const int* cnt, void* fout,
                      int bound, int pstride, hipStream_t stream)
{
    constexpr int NT = COUT / 16;
    static_assert(CIN % 32 == 0 && COUT % 16 == 0 && NT % CT == 0, "shape");
    dim3 g(cdiv_h(bound, RT * 64), NT / CT);
    conv_mfma_k<CIN, COUT, RT, CT, OUTF32><<<g, 256, 0, stream>>>(fin, Wp, pairs, cnt,
                                                                  fout, pstride);
}

extern "C" void kernel_launch(void* const* d_in, const int* in_sizes, int n_in,
                              void* d_out, int out_size, void* d_ws, size_t ws_size,
                              hipStream_t stream)
{
    const float* feats0 = (const float*)d_in[0];
    const int*   coors  = (const int*)d_in[1];
    const float* w[14];
    for (int i = 0; i < 14; ++i) w[i] = (const float*)d_in[3 + i];
    float* out = (float*)d_out;
    const int N = in_sizes[0] / 3;

    // ---- workspace carve-up ----
    char* p = (char*)d_ws;
    int* grid   = (int*)p; p += (size_t)128 * 128 * 128 * 4;  // 8 MB
    int* occ    = (int*)p; p += (size_t)64 * 64 * 64 * 4;     // 1 MB
    int* counts = (int*)p; p += 256;
    int* bsum   = (int*)p; p += 256;
    int* boff   = (int*)p; p += 256;
    int* pairs  = (int*)p; p += (size_t)27 * N * 4;
    int* coordsA = (int*)p; p += (size_t)N * 16;
    int* coordsB = (int*)p; p += (size_t)N * 16;
    unsigned short* featA = (unsigned short*)p; p += (size_t)N * 96 * 2;
    unsigned short* featB = (unsigned short*)p; p += (size_t)N * 96 * 2;
    unsigned short* wpBase = (unsigned short*)p;

    // packed weight offsets for layers 1..13
    static const int CH[14][2] = {{3,64},{64,64},{64,96},{96,96},{96,128},{128,128},
                                  {128,160},{160,160},{160,192},{192,192},{192,224},
                                  {224,224},{224,256},{256,256}};
    unsigned short* wp[14];
    {
        size_t off = 0;
        for (int i = 1; i < 14; ++i) {
            wp[i] = wpBase + off;
            off += (size_t)27 * CH[i][0] * CH[i][1];
        }
    }

    int bounds[7];
    for (int l = 0; l < 7; ++l) {
        int S = 128 >> l, c = S * S * S;
        bounds[l] = N < c ? N : c;
    }

    set_count_k<<<1, 1, 0, stream>>>(counts, N);
    hipMemsetAsync(d_out, 0, (size_t)out_size * 4, stream);

    // pack all MFMA weights (bf16 fragment layout)
    for (int i = 1; i < 14; ++i) {
        int nthreads = 27 * CH[i][0] * CH[i][1] / 8;
        pack_w_k<<<cdiv_h(nthreads, 256), 256, 0, stream>>>(w[i], wp[i], CH[i][0], CH[i][1]);
    }

    auto build_level = [&](const int* coordsL, int lvl) {
        int S = 128 >> lvl;
        hipMemsetAsync(grid, 0xFF, (size_t)S * S * S * 4, stream);
        int blocks = cdiv_h(bounds[lvl], 256);
        scatter_grid_k<<<blocks, 256, 0, stream>>>(coordsL, counts + lvl, grid, S);
        build_pairs_k<<<blocks, 256, 0, stream>>>(coordsL, counts + lvl, grid, pairs, N, S);
    };

    auto do_pool = [&](const int* coordsL, int lvl, const unsigned short* fin,
                       unsigned short* fout, int C, int* coordsOut) {
        int S = 128 >> lvl, Sh = S / 2, P = Sh * Sh * Sh;
        hipMemsetAsync(occ, 0, (size_t)P * 4, stream);
        mark_occ_k<<<cdiv_h(bounds[lvl], 256), 256, 0, stream>>>(coordsL, counts + lvl, occ, Sh);
        int nb = cdiv_h(P, 4096);
        scan_sum_k<<<nb, 256, 0, stream>>>(occ, P, bsum);
        scan_offsets_k<<<1, 64, 0, stream>>>(bsum, nb, boff, counts + lvl + 1);
        scan_emit_k<<<nb, 256, 0, stream>>>(occ, P, boff, coordsOut, Sh);
        int total = bounds[lvl + 1] * C;
        pool_max_k<<<cdiv_h(total, 256), 256, 0, stream>>>(fin, grid, coordsOut,
                                                           counts + lvl + 1, fout, C, S);
    };

    // ---- level 0 ----
    build_level(coors, 0);
    conv0_k<<<cdiv_h(bounds[0], 16), 256, 0, stream>>>(feats0, w[0], pairs, counts + 0,
                                                       featA, N);
    launch_cm<64, 64, 4, 4, false>(featA, wp[1], pairs, counts + 0, featB, bounds[0], N, stream);
    do_pool(coors, 0, featB, featA, 64, coordsA);
    // ---- level 1 ----
    build_level(coordsA, 1);
    launch_cm<64, 96, 4, 6, false>(featA, wp[2], pairs, counts + 1, featB, bounds[1], N, stream);
    launch_cm<96, 96, 4, 6, false>(featB, wp[3], pairs, counts + 1, featA, bounds[1], N, stream);
    do_pool(coordsA, 1, featA, featB, 96, coordsB);
    // ---- level 2 ----
    build_level(coordsB, 2);
    launch_cm<96, 128, 2, 4, false>(featB, wp[4], pairs, counts + 2, featA, bounds[2], N, stream);
    launch_cm<128, 128, 2, 4, false>(featA, wp[5], pairs, counts + 2, featB, bounds[2], N, stream);
    do_pool(coordsB, 2, featB, featA, 128, coordsA);
    // ---- level 3 ----
    build_level(coordsA, 3);
    launch_cm<128, 160, 1, 2, false>(featA, wp[6], pairs, counts + 3, featB, bounds[3], N, stream);
    launch_cm<160, 160, 1, 2, false>(featB, wp[7], pairs, counts + 3, featA, bounds[3], N, stream);
    do_pool(coordsA, 3, featA, featB, 160, coordsB);
    // ---- level 4 ----
    build_level(coordsB, 4);
    launch_cm<160, 192, 1, 2, false>(featB, wp[8], pairs, counts + 4, featA, bounds[4], N, stream);
    launch_cm<192, 192, 1, 2, false>(featA, wp[9], pairs, counts + 4, featB, bounds[4], N, stream);
    do_pool(coordsB, 4, featB, featA, 192, coordsA);
    // ---- level 5 ----
    build_level(coordsA, 5);
    launch_cm<192, 224, 1, 2, false>(featA, wp[10], pairs, counts + 5, featB, bounds[5], N, stream);
    launch_cm<224, 224, 1, 2, false>(featB, wp[11], pairs, counts + 5, featA, bounds[5], N, stream);
    do_pool(coordsA, 5, featA, featB, 224, coordsB);
    // ---- level 6 ----
    build_level(coordsB, 6);
    launch_cm<224, 256, 1, 2, false>(featB, wp[12], pairs, counts + 6, featA, bounds[6], N, stream);
    launch_cm<256, 256, 1, 2, true>(featA, wp[13], pairs, counts + 6, out, bounds[6], N, stream);
}

// Round 3
// 1001.741 us; speedup vs baseline: 9.3272x; 1.1631x over previous
//
#include <hip/hip_runtime.h>
#include <cstdint>
#include <cstddef>

// ---------------------------------------------------------------------------
// Submanifold sparse conv net, MFMA bf16 implicit-GEMM version.
// Round 3: occupancy + ILP (small tiles, grid.y cout-split, load-burst per tap,
// pairs prefetch, fused weight packing).
// ---------------------------------------------------------------------------

typedef __attribute__((ext_vector_type(8))) short short8v;
typedef __attribute__((ext_vector_type(4))) float f32x4;

static inline int cdiv_h(int a, int b) { return (a + b - 1) / b; }

__device__ inline unsigned short f2bf(float f) {
    unsigned int u = __builtin_bit_cast(unsigned int, f);
    u += 0x7FFFu + ((u >> 16) & 1u);
    return (unsigned short)(u >> 16);
}
__device__ inline float bf2f(unsigned short h) {
    unsigned int u = ((unsigned int)h) << 16;
    return __builtin_bit_cast(float, u);
}

__global__ void set_count_k(int* counts, int n) { counts[0] = n; }

__global__ void scatter_grid_k(const int* __restrict__ coords, const int* __restrict__ cnt,
                               int* __restrict__ grid, int S)
{
    int i = blockIdx.x * blockDim.x + threadIdx.x;
    if (i >= cnt[0]) return;
    int z = coords[i * 4 + 1], y = coords[i * 4 + 2], x = coords[i * 4 + 3];
    grid[(z * S + y) * S + x] = i;
}

__global__ void build_pairs_k(const int* __restrict__ coords, const int* __restrict__ cnt,
                              const int* __restrict__ grid, int* __restrict__ pairs,
                              int pstride, int S)
{
    int i = blockIdx.x * blockDim.x + threadIdx.x;
    if (i >= cnt[0]) return;
    int z = coords[i * 4 + 1], y = coords[i * 4 + 2], x = coords[i * 4 + 3];
#pragma unroll
    for (int k = 0; k < 27; ++k) {
        int nz = z + k / 9 - 1;
        int ny = y + (k / 3) % 3 - 1;
        int nx = x + k % 3 - 1;
        int v = -1;
        if (nz >= 0 && nz < S && ny >= 0 && ny < S && nx >= 0 && nx < S)
            v = grid[(nz * S + ny) * S + nx];
        pairs[(size_t)k * pstride + i] = v;
    }
}

// ---- fused weight pre-pack: fp32 [27][CIN][COUT] -> bf16 fragment tiles -----
// tile id = (k*NS + s)*NT + t ; within tile, lane l holds 8 contiguous bf16 =
// W[k][s*32 + (l>>4)*8 + j][t*16 + (l&15)], j=0..7.
struct PackArgs {
    const float* src[13];
    unsigned short* dst[13];
    int cin[13];
    int cout[13];
    int tileStart[14];
};

__global__ __launch_bounds__(256) void pack_all_k(PackArgs pa)
{
    int g = blockIdx.x * 4 + ((int)threadIdx.x >> 6);
    int lane = (int)threadIdx.x & 63;
    if (g >= pa.tileStart[13]) return;
    int li = 0;
    while (li < 12 && g >= pa.tileStart[li + 1]) ++li;
    int tile = g - pa.tileStart[li];
    int CIN = pa.cin[li], COUT = pa.cout[li];
    int NS = CIN >> 5, NT = COUT >> 4;
    int t = tile % NT;
    int s = (tile / NT) % NS;
    int k = tile / (NT * NS);
    int kabs = s * 32 + (lane >> 4) * 8;
    int c = t * 16 + (lane & 15);
    const float* src = pa.src[li] + ((size_t)(k * CIN + kabs)) * COUT + c;
    unsigned short* dst = pa.dst[li] + (size_t)tile * 512 + lane * 8;
#pragma unroll
    for (int j = 0; j < 8; ++j) dst[j] = f2bf(src[(size_t)j * COUT]);
}

// ---- first layer (CIN=3) fp32 vector, writes bf16 ---------------------------
__global__ __launch_bounds__(256) void conv0_k(
    const float* __restrict__ fin, const float* __restrict__ W,
    const int* __restrict__ pairs, const int* __restrict__ cnt,
    unsigned short* __restrict__ fout, int pstride)
{
    const int row = blockIdx.x * 16 + ((int)threadIdx.x >> 4);
    const int cg = ((int)threadIdx.x & 15) * 4;
    if (row >= cnt[0]) return;
    float a0 = 0, a1 = 0, a2 = 0, a3 = 0;
    for (int k = 0; k < 27; ++k) {
        int nb = pairs[(size_t)k * pstride + row];
        if (nb < 0) continue;
        const float* fr = fin + (size_t)nb * 3;
        const float* wk = W + (size_t)k * 3 * 64 + cg;
#pragma unroll
        for (int ci = 0; ci < 3; ++ci) {
            float f = fr[ci];
            float4 w = *reinterpret_cast<const float4*>(wk + ci * 64);
            a0 += f * w.x; a1 += f * w.y; a2 += f * w.z; a3 += f * w.w;
        }
    }
    size_t o = (size_t)row * 64 + cg;
    fout[o] = f2bf(a0); fout[o + 1] = f2bf(a1);
    fout[o + 2] = f2bf(a2); fout[o + 3] = f2bf(a3);
}

// ---- MFMA conv: block = 4 waves; wave = RT row-tiles x CT cout-tiles.
// Per tap: prefetched pairs -> burst all A gathers + B loads -> MFMA burst.
template <int CIN, int COUT, int RT, int CT, bool OUTF32>
__global__ __launch_bounds__(256, 4) void conv_mfma_k(
    const unsigned short* __restrict__ fin, const unsigned short* __restrict__ Wp,
    const int* __restrict__ pairs, const int* __restrict__ cnt,
    void* __restrict__ fout, int pstride)
{
    constexpr int NS = CIN / 32, NT = COUT / 16;
    const int lane = (int)threadIdx.x & 63;
    const int wave = (int)threadIdx.x >> 6;
    const int l15 = lane & 15, lhi = lane >> 4;
    const int M = cnt[0];
    const int rowBase = (blockIdx.x * 4 + wave) * (RT * 16);
    if (rowBase >= M) return;
    const int ct0 = blockIdx.y * CT;

    f32x4 acc[RT][CT];
#pragma unroll
    for (int a = 0; a < RT; ++a)
#pragma unroll
        for (int b = 0; b < CT; ++b) acc[a][b] = (f32x4){0.f, 0.f, 0.f, 0.f};

    int row[RT];
#pragma unroll
    for (int rt = 0; rt < RT; ++rt) row[rt] = rowBase + rt * 16 + l15;

    int nbN[RT];
#pragma unroll
    for (int rt = 0; rt < RT; ++rt)
        nbN[rt] = (row[rt] < M) ? pairs[row[rt]] : -1;

    for (int k = 0; k < 27; ++k) {
        int nb[RT];
#pragma unroll
        for (int rt = 0; rt < RT; ++rt) nb[rt] = nbN[rt];
        if (k < 26) {
#pragma unroll
            for (int rt = 0; rt < RT; ++rt)
                nbN[rt] = (row[rt] < M) ? pairs[(size_t)(k + 1) * pstride + row[rt]] : -1;
        }
        int act[RT];
        bool anyAct = false;
#pragma unroll
        for (int rt = 0; rt < RT; ++rt) {
            act[rt] = __any(nb[rt] >= 0);
            anyAct = anyAct || (act[rt] != 0);
        }
        if (!anyAct) continue;

        const unsigned short* wk = Wp + (size_t)k * NS * NT * 512 + (size_t)lane * 8;
        short8v bfr[NS][CT];
#pragma unroll
        for (int s = 0; s < NS; ++s)
#pragma unroll
            for (int t = 0; t < CT; ++t)
                bfr[s][t] = *reinterpret_cast<const short8v*>(
                    wk + ((size_t)s * NT + ct0 + t) * 512);

        short8v afr[NS][RT];
#pragma unroll
        for (int s = 0; s < NS; ++s)
#pragma unroll
            for (int rt = 0; rt < RT; ++rt) {
                afr[s][rt] = (short8v){};
                if (nb[rt] >= 0)
                    afr[s][rt] = *reinterpret_cast<const short8v*>(
                        fin + (size_t)nb[rt] * CIN + s * 32 + lhi * 8);
            }

#pragma unroll
        for (int s = 0; s < NS; ++s)
#pragma unroll
            for (int rt = 0; rt < RT; ++rt) {
                if (!act[rt]) continue;
#pragma unroll
                for (int t = 0; t < CT; ++t)
                    acc[rt][t] = __builtin_amdgcn_mfma_f32_16x16x32_bf16(
                        afr[s][rt], bfr[s][t], acc[rt][t], 0, 0, 0);
            }
    }

    // epilogue: C layout col = lane&15, row = (lane>>4)*4 + reg
#pragma unroll
    for (int rt = 0; rt < RT; ++rt) {
#pragma unroll
        for (int j = 0; j < 4; ++j) {
            int r = rowBase + rt * 16 + lhi * 4 + j;
            if (r >= M) continue;
#pragma unroll
            for (int t = 0; t < CT; ++t) {
                int c = (ct0 + t) * 16 + l15;
                if constexpr (OUTF32)
                    ((float*)fout)[(size_t)r * COUT + c] = acc[rt][t][j];
                else
                    ((unsigned short*)fout)[(size_t)r * COUT + c] = f2bf(acc[rt][t][j]);
            }
        }
    }
}

// ---- pooling structure: multi-block scan ------------------------------------
__global__ void mark_occ_k(const int* __restrict__ coords, const int* __restrict__ cnt,
                           int* __restrict__ occ, int Sh)
{
    int i = blockIdx.x * blockDim.x + threadIdx.x;
    if (i >= cnt[0]) return;
    int z = coords[i * 4 + 1] >> 1, y = coords[i * 4 + 2] >> 1, x = coords[i * 4 + 3] >> 1;
    occ[(z * Sh + y) * Sh + x] = 1;
}

__global__ __launch_bounds__(256) void scan_sum_k(const int* __restrict__ occ, int P,
                                                  int* __restrict__ bsum)
{
    int base = blockIdx.x * 4096 + (int)threadIdx.x * 16;
    int s = 0;
#pragma unroll
    for (int j = 0; j < 16; ++j) { int i = base + j; s += (i < P) ? occ[i] : 0; }
    for (int off = 1; off < 64; off <<= 1) s += __shfl_xor(s, off);
    __shared__ int ws[4];
    if ((threadIdx.x & 63) == 0) ws[threadIdx.x >> 6] = s;
    __syncthreads();
    if (threadIdx.x == 0) bsum[blockIdx.x] = ws[0] + ws[1] + ws[2] + ws[3];
}

__global__ void scan_offsets_k(const int* __restrict__ bsum, int nb,
                               int* __restrict__ boff, int* __restrict__ cntOut)
{
    int lane = threadIdx.x;  // 64 threads, nb <= 64
    int v = (lane < nb) ? bsum[lane] : 0;
    int incl = v;
    for (int off = 1; off < 64; off <<= 1) {
        int t = __shfl_up(incl, off);
        if (lane >= off) incl += t;
    }
    if (lane < nb) boff[lane] = incl - v;
    if (lane == 63) cntOut[0] = incl;
}

__global__ __launch_bounds__(256) void scan_emit_k(const int* __restrict__ occ, int P,
                                                   const int* __restrict__ boff,
                                                   int* __restrict__ newcoords, int Sh)
{
    __shared__ int ws[4];
    int tid = threadIdx.x;
    int base = blockIdx.x * 4096 + tid * 16;
    int v[16];
    int s = 0;
#pragma unroll
    for (int j = 0; j < 16; ++j) { int i = base + j; v[j] = (i < P) ? occ[i] : 0; s += v[j]; }
    int mysum = s;
    int incl = s;
    for (int off = 1; off < 64; off <<= 1) {
        int t = __shfl_up(incl, off);
        if ((tid & 63) >= off) incl += t;
    }
    if ((tid & 63) == 63) ws[tid >> 6] = incl;
    __syncthreads();
    int waveOff = 0;
    for (int w = 0; w < (tid >> 6); ++w) waveOff += ws[w];
    int r = boff[blockIdx.x] + waveOff + incl - mysum;
    const int SS = Sh * Sh;
#pragma unroll
    for (int j = 0; j < 16; ++j) {
        if (v[j]) {
            int c = base + j;
            newcoords[r * 4 + 0] = 0;
            newcoords[r * 4 + 1] = c / SS;
            newcoords[r * 4 + 2] = (c % SS) / Sh;
            newcoords[r * 4 + 3] = c % Sh;
            ++r;
        }
    }
}

__global__ void pool_max_k(const unsigned short* __restrict__ fin, const int* __restrict__ gridPrev,
                           const int* __restrict__ newcoords, const int* __restrict__ cnt,
                           unsigned short* __restrict__ fout, int C, int Sprev)
{
    int idx = blockIdx.x * blockDim.x + threadIdx.x;
    int r = idx / C, c = idx % C;
    if (r >= cnt[0]) return;
    int z2 = newcoords[r * 4 + 1] * 2;
    int y2 = newcoords[r * 4 + 2] * 2;
    int x2 = newcoords[r * 4 + 3] * 2;
    float best = -3.4e38f;
    unsigned short bb = 0;
#pragma unroll
    for (int d = 0; d < 8; ++d) {
        int z = z2 + (d >> 2), y = y2 + ((d >> 1) & 1), x = x2 + (d & 1);
        int j = gridPrev[(z * Sprev + y) * Sprev + x];
        if (j >= 0) {
            unsigned short u = fin[(size_t)j * C + c];
            float f = bf2f(u);
            if (f > best) { best = f; bb = u; }
        }
    }
    fout[(size_t)r * C + c] = bb;
}

// ---------------------------------------------------------------------------

template <int CIN, int COUT, int RT, int CT, bool OUTF32>
static void launch_cm(const unsigned short* fin, const unsigned short* Wp,
                      const int* pairs, const int* cnt, void* fout,
                      int bound, int pstride, hipStream_t stream)
{
    constexpr int NT = COUT / 16;
    static_assert(CIN % 32 == 0 && COUT % 16 == 0 && NT % CT == 0, "shape");
    dim3 g(cdiv_h(bound, RT * 64), NT / CT);
    conv_mfma_k<CIN, COUT, RT, CT, OUTF32><<<g, 256, 0, stream>>>(fin, Wp, pairs, cnt,
                                                                  fout, pstride);
}

extern "C" void kernel_launch(void* const* d_in, const int* in_sizes, int n_in,
                              void* d_out, int out_size, void* d_ws, size_t ws_size,
                              hipStream_t stream)
{
    const float* feats0 = (const float*)d_in[0];
    const int*   coors  = (const int*)d_in[1];
    const float* w[14];
    for (int i = 0; i < 14; ++i) w[i] = (const float*)d_in[3 + i];
    float* out = (float*)d_out;
    const int N = in_sizes[0] / 3;

    // ---- workspace carve-up ----
    char* p = (char*)d_ws;
    int* grid   = (int*)p; p += (size_t)128 * 128 * 128 * 4;  // 8 MB
    int* occ    = (int*)p; p += (size_t)64 * 64 * 64 * 4;     // 1 MB
    int* counts = (int*)p; p += 256;
    int* bsum   = (int*)p; p += 256;
    int* boff   = (int*)p; p += 256;
    int* pairs  = (int*)p; p += (size_t)27 * N * 4;
    int* coordsA = (int*)p; p += (size_t)N * 16;
    int* coordsB = (int*)p; p += (size_t)N * 16;
    unsigned short* featA = (unsigned short*)p; p += (size_t)N * 96 * 2;
    unsigned short* featB = (unsigned short*)p; p += (size_t)N * 96 * 2;
    unsigned short* wpBase = (unsigned short*)p;

    static const int CH[14][2] = {{3,64},{64,64},{64,96},{96,96},{96,128},{128,128},
                                  {128,160},{160,160},{160,192},{192,192},{192,224},
                                  {224,224},{224,256},{256,256}};
    unsigned short* wp[14];
    PackArgs pa;
    {
        size_t off = 0;
        int ts = 0;
        for (int i = 1; i < 14; ++i) {
            wp[i] = wpBase + off;
            off += (size_t)27 * CH[i][0] * CH[i][1];
            pa.src[i - 1] = w[i];
            pa.dst[i - 1] = wp[i];
            pa.cin[i - 1] = CH[i][0];
            pa.cout[i - 1] = CH[i][1];
            pa.tileStart[i - 1] = ts;
            ts += 27 * (CH[i][0] / 32) * (CH[i][1] / 16);
        }
        pa.tileStart[13] = ts;
    }

    int bounds[7];
    for (int l = 0; l < 7; ++l) {
        int S = 128 >> l, c = S * S * S;
        bounds[l] = N < c ? N : c;
    }

    set_count_k<<<1, 1, 0, stream>>>(counts, N);
    hipMemsetAsync(d_out, 0, (size_t)out_size * 4, stream);
    pack_all_k<<<cdiv_h(pa.tileStart[13], 4), 256, 0, stream>>>(pa);

    auto build_level = [&](const int* coordsL, int lvl) {
        int S = 128 >> lvl;
        hipMemsetAsync(grid, 0xFF, (size_t)S * S * S * 4, stream);
        int blocks = cdiv_h(bounds[lvl], 256);
        scatter_grid_k<<<blocks, 256, 0, stream>>>(coordsL, counts + lvl, grid, S);
        build_pairs_k<<<blocks, 256, 0, stream>>>(coordsL, counts + lvl, grid, pairs, N, S);
    };

    auto do_pool = [&](const int* coordsL, int lvl, const unsigned short* fin,
                       unsigned short* fout, int C, int* coordsOut) {
        int S = 128 >> lvl, Sh = S / 2, P = Sh * Sh * Sh;
        hipMemsetAsync(occ, 0, (size_t)P * 4, stream);
        mark_occ_k<<<cdiv_h(bounds[lvl], 256), 256, 0, stream>>>(coordsL, counts + lvl, occ, Sh);
        int nb = cdiv_h(P, 4096);
        scan_sum_k<<<nb, 256, 0, stream>>>(occ, P, bsum);
        scan_offsets_k<<<1, 64, 0, stream>>>(bsum, nb, boff, counts + lvl + 1);
        scan_emit_k<<<nb, 256, 0, stream>>>(occ, P, boff, coordsOut, Sh);
        int total = bounds[lvl + 1] * C;
        pool_max_k<<<cdiv_h(total, 256), 256, 0, stream>>>(fin, grid, coordsOut,
                                                           counts + lvl + 1, fout, C, S);
    };

    // ---- level 0 ----
    build_level(coors, 0);
    conv0_k<<<cdiv_h(bounds[0], 16), 256, 0, stream>>>(feats0, w[0], pairs, counts + 0,
                                                       featA, N);
    launch_cm<64, 64, 2, 2, false>(featA, wp[1], pairs, counts + 0, featB, bounds[0], N, stream);
    do_pool(coors, 0, featB, featA, 64, coordsA);
    // ---- level 1 ----
    build_level(coordsA, 1);
    launch_cm<64, 96, 2, 3, false>(featA, wp[2], pairs, counts + 1, featB, bounds[1], N, stream);
    launch_cm<96, 96, 2, 3, false>(featB, wp[3], pairs, counts + 1, featA, bounds[1], N, stream);
    do_pool(coordsA, 1, featA, featB, 96, coordsB);
    // ---- level 2 ----
    build_level(coordsB, 2);
    launch_cm<96, 128, 1, 2, false>(featB, wp[4], pairs, counts + 2, featA, bounds[2], N, stream);
    launch_cm<128, 128, 1, 2, false>(featA, wp[5], pairs, counts + 2, featB, bounds[2], N, stream);
    do_pool(coordsB, 2, featB, featA, 128, coordsA);
    // ---- level 3 ----
    build_level(coordsA, 3);
    launch_cm<128, 160, 1, 2, false>(featA, wp[6], pairs, counts + 3, featB, bounds[3], N, stream);
    launch_cm<160, 160, 1, 2, false>(featB, wp[7], pairs, counts + 3, featA, bounds[3], N, stream);
    do_pool(coordsA, 3, featA, featB, 160, coordsB);
    // ---- level 4 ----
    build_level(coordsB, 4);
    launch_cm<160, 192, 1, 2, false>(featB, wp[8], pairs, counts + 4, featA, bounds[4], N, stream);
    launch_cm<192, 192, 1, 2, false>(featA, wp[9], pairs, counts + 4, featB, bounds[4], N, stream);
    do_pool(coordsB, 4, featB, featA, 192, coordsA);
    // ---- level 5 ----
    build_level(coordsA, 5);
    launch_cm<192, 224, 1, 2, false>(featA, wp[10], pairs, counts + 5, featB, bounds[5], N, stream);
    launch_cm<224, 224, 1, 2, false>(featB, wp[11], pairs, counts + 5, featA, bounds[5], N, stream);
    do_pool(coordsA, 5, featA, featB, 224, coordsB);
    // ---- level 6 ----
    build_level(coordsB, 6);
    launch_cm<224, 256, 1, 2, false>(featB, wp[12], pairs, counts + 6, featA, bounds[6], N, stream);
    launch_cm<256, 256, 1, 2, true>(featA, wp[13], pairs, counts + 6, out, bounds[6], N, stream);
}